// Round 16
// baseline (12018.739 us; speedup 1.0000x reference)
//
#include <hip/hip_runtime.h>
#include <hip/hip_bf16.h>

typedef _Float16 f16;
typedef f16  f16x8 __attribute__((ext_vector_type(8)));
typedef float f32x4 __attribute__((ext_vector_type(4)));

__device__ __forceinline__ f16x8 ld8h(const f16* p){ return *reinterpret_cast<const f16x8*>(p); }
__device__ __forceinline__ void fsplit(float x, f16* hi, f16* lo){
    f16 h=(f16)x; *hi=h; *lo=(f16)((x-(float)h)*4096.0f);
}
#define MFMA16(a,b,c) __builtin_amdgcn_mfma_f32_16x16x32_f16((a),(b),(c),0,0,0)
// fragment-major offset: 16(n)x32(k) fragment = 512 contiguous f16; within-frag = lane*8+e
__device__ __forceinline__ size_t fragoff(int n, int k, int Kc){
    return ((size_t)(n>>4)*Kc + (k>>5))*512 + (size_t)((((k&31)>>3)*16 + (n&15))*8 + (k&7));
}

// ---------------- element counts ----------------
constexpr size_t NXE   = 128ull*256*128;
constexpr size_t NPM   = 1024ull*4096;
constexpr size_t NWIH0 = 3072ull*384;
constexpr size_t NWIH12= 3072ull*256;
constexpr size_t NWIH3 = 3456ull*256;
constexpr size_t NWHH  = 3072ull*1024;
constexpr size_t NWHH3 = 3456ull*1152;
constexpr size_t NCTX  = 128ull*1024;
constexpr size_t NHMX  = 128ull*1152;

// ---------------- workspace offsets (bytes) ----------------
constexpr size_t OFF_XH    = 0;
constexpr size_t OFF_XL    = OFF_XH + NXE*2;
constexpr size_t OFF_PMH   = OFF_XL + NXE*2;
constexpr size_t OFF_PML   = OFF_PMH + NPM*2;
constexpr size_t OFF_WIHH0 = OFF_PML + NPM*2;
constexpr size_t OFF_WIHH1 = OFF_WIHH0 + NWIH0*2;
constexpr size_t OFF_WIHH2 = OFF_WIHH1 + NWIH12*2;
constexpr size_t OFF_WIHH3 = OFF_WIHH2 + NWIH12*2;
constexpr size_t OFF_WIHL0 = OFF_WIHH3 + NWIH3*2;
constexpr size_t OFF_WIHL1 = OFF_WIHL0 + NWIH0*2;
constexpr size_t OFF_WIHL2 = OFF_WIHL1 + NWIH12*2;
constexpr size_t OFF_WIHL3 = OFF_WIHL2 + NWIH12*2;
constexpr size_t OFF_WHHH0 = OFF_WIHL3 + NWIH3*2;
constexpr size_t OFF_WHHH1 = OFF_WHHH0 + NWHH*2;
constexpr size_t OFF_WHHH2 = OFF_WHHH1 + NWHH*2;
constexpr size_t OFF_WHHH3 = OFF_WHHH2 + NWHH*2;
constexpr size_t OFF_WHHL0 = OFF_WHHH3 + NWHH3*2;
constexpr size_t OFF_WHHL1 = OFF_WHHL0 + NWHH*2;
constexpr size_t OFF_WHHL2 = OFF_WHHL1 + NWHH*2;
constexpr size_t OFF_WHHL3 = OFF_WHHL2 + NWHH*2;
constexpr size_t OFF_C0H   = OFF_WHHL3 + NWHH3*2;   // center_init, h-layout, 4 modules
constexpr size_t OFF_C0L   = OFF_C0H + 4*NHMX*2;
constexpr size_t OFF_CTXH  = OFF_C0L + 4*NHMX*2;
constexpr size_t OFF_CTXL  = OFF_CTXH + NCTX*2;
constexpr size_t OFF_HH    = OFF_CTXL + NCTX*2;     // [(p*4+i)]
constexpr size_t OFF_HL    = OFF_HH + 8*NHMX*2;
constexpr size_t WS_NEED   = OFF_HL + 8*NHMX*2;     // ~109 MB

__device__ __forceinline__ f16* hh_ptr(char* ws,int p,int i){ return (f16*)(ws+OFF_HH+((size_t)(p*4+i))*NHMX*2); }
__device__ __forceinline__ f16* hl_ptr(char* ws,int p,int i){ return (f16*)(ws+OFF_HL+((size_t)(p*4+i))*NHMX*2); }

// ---------------- prep: repack to fragment-major ----------------
__global__ void k_repack_w(const float* __restrict__ src, f16* __restrict__ hi,
                           f16* __restrict__ lo, int K){
    int n = blockIdx.x;
    const float* row = src + (size_t)n*K;
    int Kc = K >> 5;
    for (int k8 = threadIdx.x*8; k8 < K; k8 += 2048) {
        f16x8 hv, lv;
        #pragma unroll
        for (int e = 0; e < 8; ++e) { f16 a,b; fsplit(row[k8+e], &a, &b); hv[e]=a; lv[e]=b; }
        size_t d = fragoff(n, k8, Kc);
        *reinterpret_cast<f16x8*>(hi + d) = hv;
        *reinterpret_cast<f16x8*>(lo + d) = lv;
    }
}

__global__ void k_repack_pm(const float* __restrict__ p0, const float* __restrict__ p1,
                            const float* __restrict__ p2, const float* __restrict__ p3,
                            f16* __restrict__ hi, f16* __restrict__ lo){
    int k0 = blockIdx.x * 8;
    for (int c = threadIdx.x; c < 1024; c += 256) {
        int i = c >> 8, nl = c & 255;
        const float* p = (i==0?p0 : i==1?p1 : i==2?p2 : p3);
        #pragma unroll
        for (int e = 0; e < 8; ++e) {
            f16 a,b; fsplit(p[(size_t)(k0+e)*256 + nl], &a, &b);
            size_t d = fragoff(c, k0+e, 128); hi[d]=a; lo[d]=b;
        }
    }
}

__global__ void k_repack_x(const float* __restrict__ src, f16* __restrict__ hi, f16* __restrict__ lo){
    size_t g = ((size_t)blockIdx.x*256 + threadIdx.x) * 8;
    if (g >= NXE) return;
    int m = (int)(g >> 15), t = (int)((g >> 7) & 255), d0 = (int)(g & 127);
    f16x8 hv, lv;
    #pragma unroll
    for (int e = 0; e < 8; ++e) { f16 a,b; fsplit(src[g+e], &a, &b); hv[e]=a; lv[e]=b; }
    size_t d = (size_t)t*16384 + fragoff(m, d0, 4);
    *reinterpret_cast<f16x8*>(hi + d) = hv;
    *reinterpret_cast<f16x8*>(lo + d) = lv;
}

__global__ void k_init_cen(const float* __restrict__ ci, char* ws){
    size_t g = ((size_t)blockIdx.x*256 + threadIdx.x) * 8;
    if (g >= 4ull*128*1024) return;
    int i = (int)(g >> 17), b = (int)((g >> 10) & 127), c = (int)(g & 1023);
    f16* hi = (f16*)(ws + OFF_C0H) + (size_t)i*NHMX;
    f16* lo = (f16*)(ws + OFF_C0L) + (size_t)i*NHMX;
    f16x8 hv, lv;
    #pragma unroll
    for (int e = 0; e < 8; ++e) { f16 a,bb; fsplit(ci[g+e], &a, &bb); hv[e]=a; lv[e]=bb; }
    size_t d = (i < 3) ? fragoff(b, c, 32) : fragoff(b, 128 + c, 36);
    *reinterpret_cast<f16x8*>(hi + d) = hv;
    *reinterpret_cast<f16x8*>(lo + d) = lv;
}

__global__ void k_init_mod(const float* __restrict__ mi, char* ws){
    size_t g = ((size_t)blockIdx.x*256 + threadIdx.x) * 8;
    if (g >= 3ull*128*1024) return;
    int i = (int)(g >> 17), b = (int)((g >> 10) & 127), j = (int)(g & 1023);
    f16 *hh = hh_ptr(ws, 0, i), *hl = hl_ptr(ws, 0, i);
    f16x8 hv, lv;
    #pragma unroll
    for (int e = 0; e < 8; ++e) { f16 a,bb; fsplit(mi[g+e], &a, &bb); hv[e]=a; lv[e]=bb; }
    size_t d = fragoff(b, j, 32);
    *reinterpret_cast<f16x8*>(hh + d) = hv;
    *reinterpret_cast<f16x8*>(hl + d) = lv;
}

__global__ void k_init_last(const float* __restrict__ ml, char* ws){
    int b = blockIdx.x;
    f16 *hh = hh_ptr(ws, 0, 3), *hl = hl_ptr(ws, 0, 3);
    for (int j = threadIdx.x*8; j < 1152; j += 2048) {
        f16x8 hv, lv;
        #pragma unroll
        for (int e = 0; e < 8; ++e) { f16 a,bb; fsplit(ml[(size_t)b*1152 + j + e], &a, &bb); hv[e]=a; lv[e]=bb; }
        size_t d = fragoff(b, j, 36);
        *reinterpret_cast<f16x8*>(hh + d) = hv;
        *reinterpret_cast<f16x8*>(hl + d) = lv;
    }
}

// ---------------- step kernel 1: ctx = center @ pm ----------------
// pm-sharing blocks (same bn, bm 0..3) differ by 64 in bid -> same XCD already.
__global__ __launch_bounds__(512) void k_ctx(char* ws, int par, int t){
    __shared__ float red[8][32][17];
    const f16* pmh  = (const f16*)(ws + OFF_PMH);
    const f16* pml  = (const f16*)(ws + OFF_PML);
    int tid = threadIdx.x, lane = tid & 63, wv = tid >> 6;
    int bm = blockIdx.x >> 6, bn = blockIdx.x & 63;
    int mod = wv >> 1, half = wv & 1;
    const int Kc_m = (mod == 3) ? 36 : 32;
    const int koff = ((mod == 3) ? 4 : 0) + half*16;
    const f16 *Ah, *Al;
    if (t == 0) {
        Ah = (const f16*)(ws + OFF_C0H) + (size_t)mod*NHMX;
        Al = (const f16*)(ws + OFF_C0L) + (size_t)mod*NHMX;
    } else {
        Ah = hh_ptr(ws, par, mod);
        Al = hl_ptr(ws, par, mod);
    }
    size_t lb = (size_t)lane*8;
    size_t a0 = ((size_t)(bm*2)*Kc_m + koff)*512 + lb;
    size_t a1 = a0 + (size_t)Kc_m*512;
    size_t bb = ((size_t)bn*128 + wv*16)*512 + lb;
    f32x4 h0={},h1={},c0={},c1={};
    #pragma unroll 8
    for (int kc = 0; kc < 16; ++kc) {
        f16x8 bh = ld8h(pmh + bb + kc*512), bl = ld8h(pml + bb + kc*512);
        f16x8 ah0 = ld8h(Ah + a0 + kc*512), al0 = ld8h(Al + a0 + kc*512);
        f16x8 ah1 = ld8h(Ah + a1 + kc*512), al1 = ld8h(Al + a1 + kc*512);
        h0 = MFMA16(ah0,bh,h0); c0 = MFMA16(al0,bh,c0); c0 = MFMA16(ah0,bl,c0);
        h1 = MFMA16(ah1,bh,h1); c1 = MFMA16(al1,bh,c1); c1 = MFMA16(ah1,bl,c1);
    }
    int rg = lane >> 4, fr = lane & 15;
    const float inv = 1.0f/4096.0f;
    #pragma unroll
    for (int rr = 0; rr < 4; ++rr) {
        red[wv][rg*4+rr][fr]      = h0[rr] + c0[rr]*inv;
        red[wv][16+rg*4+rr][fr]   = h1[rr] + c1[rr]*inv;
    }
    __syncthreads();
    int r = tid >> 4, c = tid & 15;
    float s = red[0][r][c]+red[1][r][c]+red[2][r][c]+red[3][r][c]
            + red[4][r][c]+red[5][r][c]+red[6][r][c]+red[7][r][c];
    int m = bm*32 + r, n = bn*16 + c;
    size_t d = fragoff(m, n, 32);
    f16* ctxh = (f16*)(ws + OFF_CTXH);
    f16* ctxl = (f16*)(ws + OFF_CTXL);
    fsplit(s, &ctxh[d], &ctxl[d]);
}

// ---------------- step kernel 2: fused gates+GRU (R15 + unroll 4) ----------------
// 528 blocks x 512 thr, lid swizzle pairs rh blocks on one XCD; waves (mp 0..1, kq 0..3);
// K-quarter per wave; one barrier; kq0 combines + GRU epilogue.
__global__ __launch_bounds__(512, 2) void k_fused(char* ws,
    const float* __restrict__ bih0, const float* __restrict__ bih1,
    const float* __restrict__ bih2, const float* __restrict__ bih3,
    const float* __restrict__ bhh0, const float* __restrict__ bhh1,
    const float* __restrict__ bhh2, const float* __restrict__ bhh3,
    float* __restrict__ out, int t, int par)
{
    __shared__ float red[3][4][64][17];   // 52.2 KB
    const int tid = threadIdx.x, lane = tid & 63, wv = tid >> 6;
    const int kq = wv & 3, mp = wv >> 2;
    const int fr = lane & 15, rg = lane >> 4;
    const int lid = (blockIdx.x & 7)*66 + (blockIdx.x >> 3);   // XCD-pairing swizzle
    const int tile = lid >> 1, rh = lid & 1;
    int i, jt;
    if (tile < 64)       { i = 0; jt = tile; }
    else if (tile < 128) { i = 1; jt = tile - 64; }
    else if (tile < 192) { i = 2; jt = tile - 128; }
    else                 { i = 3; jt = tile - 192; }
    const int H  = (i == 3) ? 1152 : 1024;
    const int K1 = (i == 0) ? 384 : 256;
    const int Kc1 = K1 >> 5, KcH = H >> 5, Ht = H >> 4;
    const int P1q = Kc1 >> 2, PHq = KcH >> 2;

    const f16* WihH = (const f16*)(ws + (i==0?OFF_WIHH0 : i==1?OFF_WIHH1 : i==2?OFF_WIHH2 : OFF_WIHH3));
    const f16* WihL = (const f16*)(ws + (i==0?OFF_WIHL0 : i==1?OFF_WIHL1 : i==2?OFF_WIHL2 : OFF_WIHL3));
    const f16* WhhH = (const f16*)(ws + (i==0?OFF_WHHH0 : i==1?OFF_WHHH1 : i==2?OFF_WHHH2 : OFF_WHHH3));
    const f16* WhhL = (const f16*)(ws + (i==0?OFF_WHHL0 : i==1?OFF_WHHL1 : i==2?OFF_WHHL2 : OFF_WHHL3));

    const size_t lb = (size_t)lane*8;
    size_t b1[3], b2[3];
    #pragma unroll
    for (int s = 0; s < 3; ++s) {
        b1[s] = ((size_t)(s*Ht + jt)*Kc1)*512 + lb;
        b2[s] = ((size_t)(s*Ht + jt)*KcH)*512 + lb;
    }
    const int mt0 = rh*4 + mp*2;

    f32x4 aRh[2]={{},{}}, aRc[2]={{},{}}, aZh[2]={{},{}}, aZc[2]={{},{}};
    f32x4 aIh[2]={{},{}}, aIc[2]={{},{}}, aNh[2]={{},{}}, aNc[2]={{},{}};

    // ---- ih GEMM (K-quarter) ----
    {
        const f16* XH_ = (const f16*)(ws + OFF_XH);
        const f16* XL_ = (const f16*)(ws + OFF_XL);
        const f16* CH_ = (const f16*)(ws + OFF_CTXH);
        const f16* CL_ = (const f16*)(ws + OFF_CTXL);
        size_t xb0 = ((size_t)(t*8 + mt0)*4)*512 + lb, xb1 = xb0 + 2048;
        size_t cb0 = ((size_t)mt0*32)*512 + lb,        cb1 = cb0 + 16384;
        const int kc0 = kq*P1q, kc1e = kc0 + P1q;
        #pragma unroll 4
        for (int kc = kc0; kc < kc1e; ++kc) {
            f16x8 ah0, al0, ah1, al1;
            if (i == 0 && kc < 4) {
                ah0 = ld8h(XH_ + xb0 + kc*512); al0 = ld8h(XL_ + xb0 + kc*512);
                ah1 = ld8h(XH_ + xb1 + kc*512); al1 = ld8h(XL_ + xb1 + kc*512);
            } else {
                const int ck = (i == 0) ? kc - 4 : i*8 + kc;
                ah0 = ld8h(CH_ + cb0 + ck*512); al0 = ld8h(CL_ + cb0 + ck*512);
                ah1 = ld8h(CH_ + cb1 + ck*512); al1 = ld8h(CL_ + cb1 + ck*512);
            }
            f16x8 bh, bl;
            bh = ld8h(WihH + b1[0] + kc*512); bl = ld8h(WihL + b1[0] + kc*512);
            aRh[0]=MFMA16(ah0,bh,aRh[0]); aRc[0]=MFMA16(al0,bh,aRc[0]); aRc[0]=MFMA16(ah0,bl,aRc[0]);
            aRh[1]=MFMA16(ah1,bh,aRh[1]); aRc[1]=MFMA16(al1,bh,aRc[1]); aRc[1]=MFMA16(ah1,bl,aRc[1]);
            bh = ld8h(WihH + b1[1] + kc*512); bl = ld8h(WihL + b1[1] + kc*512);
            aZh[0]=MFMA16(ah0,bh,aZh[0]); aZc[0]=MFMA16(al0,bh,aZc[0]); aZc[0]=MFMA16(ah0,bl,aZc[0]);
            aZh[1]=MFMA16(ah1,bh,aZh[1]); aZc[1]=MFMA16(al1,bh,aZc[1]); aZc[1]=MFMA16(ah1,bl,aZc[1]);
            bh = ld8h(WihH + b1[2] + kc*512); bl = ld8h(WihL + b1[2] + kc*512);
            aIh[0]=MFMA16(ah0,bh,aIh[0]); aIc[0]=MFMA16(al0,bh,aIc[0]); aIc[0]=MFMA16(ah0,bl,aIc[0]);
            aIh[1]=MFMA16(ah1,bh,aIh[1]); aIc[1]=MFMA16(al1,bh,aIc[1]); aIc[1]=MFMA16(ah1,bl,aIc[1]);
        }
    }
    // ---- hh GEMM (K-quarter) ----
    {
        const f16* HHp = hh_ptr(ws, par, i);
        const f16* HLp = hl_ptr(ws, par, i);
        size_t hb0 = ((size_t)mt0*KcH)*512 + lb, hb1 = hb0 + (size_t)KcH*512;
        const int kc0 = kq*PHq, kc1e = kc0 + PHq;
        #pragma unroll 4
        for (int kc = kc0; kc < kc1e; ++kc) {
            f16x8 ah0 = ld8h(HHp + hb0 + kc*512), al0 = ld8h(HLp + hb0 + kc*512);
            f16x8 ah1 = ld8h(HHp + hb1 + kc*512), al1 = ld8h(HLp + hb1 + kc*512);
            f16x8 bh, bl;
            bh = ld8h(WhhH + b2[0] + kc*512); bl = ld8h(WhhL + b2[0] + kc*512);
            aRh[0]=MFMA16(ah0,bh,aRh[0]); aRc[0]=MFMA16(al0,bh,aRc[0]); aRc[0]=MFMA16(ah0,bl,aRc[0]);
            aRh[1]=MFMA16(ah1,bh,aRh[1]); aRc[1]=MFMA16(al1,bh,aRc[1]); aRc[1]=MFMA16(ah1,bl,aRc[1]);
            bh = ld8h(WhhH + b2[1] + kc*512); bl = ld8h(WhhL + b2[1] + kc*512);
            aZh[0]=MFMA16(ah0,bh,aZh[0]); aZc[0]=MFMA16(al0,bh,aZc[0]); aZc[0]=MFMA16(ah0,bl,aZc[0]);
            aZh[1]=MFMA16(ah1,bh,aZh[1]); aZc[1]=MFMA16(al1,bh,aZc[1]); aZc[1]=MFMA16(ah1,bl,aZc[1]);
            bh = ld8h(WhhH + b2[2] + kc*512); bl = ld8h(WhhL + b2[2] + kc*512);
            aNh[0]=MFMA16(ah0,bh,aNh[0]); aNc[0]=MFMA16(al0,bh,aNc[0]); aNc[0]=MFMA16(ah0,bl,aNc[0]);
            aNh[1]=MFMA16(ah1,bh,aNh[1]); aNc[1]=MFMA16(al1,bh,aNc[1]); aNc[1]=MFMA16(ah1,bl,aNc[1]);
        }
    }

    const float inv = 1.0f/4096.0f;
    const int r16 = rg*4;
    if (kq != 0) {
        #pragma unroll
        for (int mi = 0; mi < 2; ++mi) {
            #pragma unroll
            for (int rr = 0; rr < 4; ++rr) {
                const int row = mp*32 + mi*16 + r16 + rr;
                red[kq-1][0][row][fr] = aRh[mi][rr] + aRc[mi][rr]*inv;
                red[kq-1][1][row][fr] = aZh[mi][rr] + aZc[mi][rr]*inv;
                red[kq-1][2][row][fr] = aIh[mi][rr] + aIc[mi][rr]*inv;
                red[kq-1][3][row][fr] = aNh[mi][rr] + aNc[mi][rr]*inv;
            }
        }
    }
    __syncthreads();
    if (kq != 0) return;

    const float* bihp = (i==0?bih0 : i==1?bih1 : i==2?bih2 : bih3);
    const float* bhhp = (i==0?bhh0 : i==1?bhh1 : i==2?bhh2 : bhh3);
    const int j = jt*16 + fr;
    const float bir = bihp[j], biz = bihp[H+j], bin = bihp[2*H+j];
    const float bhr = bhhp[j], bhz = bhhp[H+j], bhn = bhhp[2*H+j];
    const f16* hhP = hh_ptr(ws, par, i);
    const f16* hlP = hl_ptr(ws, par, i);
    f16 *hhN = hh_ptr(ws, par^1, i), *hlN = hl_ptr(ws, par^1, i);
    #pragma unroll
    for (int mi = 0; mi < 2; ++mi) {
        #pragma unroll
        for (int rr = 0; rr < 4; ++rr) {
            const int row = mp*32 + mi*16 + r16 + rr;
            float r_  = aRh[mi][rr] + aRc[mi][rr]*inv
                      + red[0][0][row][fr] + red[1][0][row][fr] + red[2][0][row][fr] + bir + bhr;
            float z_  = aZh[mi][rr] + aZc[mi][rr]*inv
                      + red[0][1][row][fr] + red[1][1][row][fr] + red[2][1][row][fr] + biz + bhz;
            float in_ = aIh[mi][rr] + aIc[mi][rr]*inv
                      + red[0][2][row][fr] + red[1][2][row][fr] + red[2][2][row][fr] + bin;
            float hn_ = aNh[mi][rr] + aNc[mi][rr]*inv
                      + red[0][3][row][fr] + red[1][3][row][fr] + red[2][3][row][fr] + bhn;
            float rgt = 1.f/(1.f + expf(-r_));
            float zgt = 1.f/(1.f + expf(-z_));
            float ngt = tanhf(in_ + rgt*hn_);
            const int m = rh*64 + row;
            size_t hd = fragoff(m, j, KcH);
            float hp = (float)hhP[hd] + (float)hlP[hd]*inv;
            float hnew = (1.f - zgt)*ngt + zgt*hp;
            fsplit(hnew, &hhN[hd], &hlN[hd]);
            if (i == 3 && j < 128)
                out[((size_t)m*256 + t)*128 + j] = hnew;
        }
    }
}

// ---------------- host ----------------
extern "C" void kernel_launch(void* const* d_in, const int* in_sizes, int n_in,
                              void* d_out, int out_size, void* d_ws, size_t ws_size,
                              hipStream_t stream)
{
    char* ws = (char*)d_ws;
    const float* inp   = (const float*)d_in[0];
    const float* cini  = (const float*)d_in[1];
    const float* mini  = (const float*)d_in[2];
    const float* mlast = (const float*)d_in[3];
    const float *pm[4], *wih[4], *whh[4], *bih[4], *bhh[4];
    for (int i = 0; i < 4; ++i) {
        pm[i]  = (const float*)d_in[4 + 5*i];
        wih[i] = (const float*)d_in[5 + 5*i];
        whh[i] = (const float*)d_in[6 + 5*i];
        bih[i] = (const float*)d_in[7 + 5*i];
        bhh[i] = (const float*)d_in[8 + 5*i];
    }
    float* out = (float*)d_out;

    k_repack_x<<<2048, 256, 0, stream>>>(inp, (f16*)(ws+OFF_XH), (f16*)(ws+OFF_XL));
    k_repack_pm<<<512, 256, 0, stream>>>(pm[0], pm[1], pm[2], pm[3],
                                         (f16*)(ws+OFF_PMH), (f16*)(ws+OFF_PML));
    k_repack_w<<<3072, 256, 0, stream>>>(wih[0], (f16*)(ws+OFF_WIHH0), (f16*)(ws+OFF_WIHL0), 384);
    k_repack_w<<<3072, 256, 0, stream>>>(wih[1], (f16*)(ws+OFF_WIHH1), (f16*)(ws+OFF_WIHL1), 256);
    k_repack_w<<<3072, 256, 0, stream>>>(wih[2], (f16*)(ws+OFF_WIHH2), (f16*)(ws+OFF_WIHL2), 256);
    k_repack_w<<<3456, 256, 0, stream>>>(wih[3], (f16*)(ws+OFF_WIHH3), (f16*)(ws+OFF_WIHL3), 256);
    k_repack_w<<<3072, 256, 0, stream>>>(whh[0], (f16*)(ws+OFF_WHHH0), (f16*)(ws+OFF_WHHL0), 1024);
    k_repack_w<<<3072, 256, 0, stream>>>(whh[1], (f16*)(ws+OFF_WHHH1), (f16*)(ws+OFF_WHHL1), 1024);
    k_repack_w<<<3072, 256, 0, stream>>>(whh[2], (f16*)(ws+OFF_WHHH2), (f16*)(ws+OFF_WHHL2), 1024);
    k_repack_w<<<3456, 256, 0, stream>>>(whh[3], (f16*)(ws+OFF_WHHH3), (f16*)(ws+OFF_WHHL3), 1152);
    k_init_cen<<<256, 256, 0, stream>>>(cini, ws);
    k_init_mod<<<192, 256, 0, stream>>>(mini, ws);
    k_init_last<<<128, 256, 0, stream>>>(mlast, ws);

    for (int t = 0; t < 256; ++t) {
        int par = t & 1;
        k_ctx<<<256, 512, 0, stream>>>(ws, par, t);
        k_fused<<<528, 512, 0, stream>>>(ws,
            bih[0], bih[1], bih[2], bih[3],
            bhh[0], bhh[1], bhh[2], bhh[3],
            out, t, par);
    }
    (void)in_sizes; (void)n_in; (void)out_size; (void)ws_size; (void)WS_NEED;
}

// Round 17
// 11784.131 us; speedup vs baseline: 1.0199x; 1.0199x over previous
//
#include <hip/hip_runtime.h>
#include <hip/hip_bf16.h>

typedef _Float16 f16;
typedef f16  f16x8 __attribute__((ext_vector_type(8)));
typedef float f32x4 __attribute__((ext_vector_type(4)));

__device__ __forceinline__ f16x8 ld8h(const f16* p){ return *reinterpret_cast<const f16x8*>(p); }
__device__ __forceinline__ void fsplit(float x, f16* hi, f16* lo){
    f16 h=(f16)x; *hi=h; *lo=(f16)((x-(float)h)*4096.0f);
}
#define MFMA16(a,b,c) __builtin_amdgcn_mfma_f32_16x16x32_f16((a),(b),(c),0,0,0)
// fragment-major offset: 16(n)x32(k) fragment = 512 contiguous f16; within-frag = lane*8+e
__device__ __forceinline__ size_t fragoff(int n, int k, int Kc){
    return ((size_t)(n>>4)*Kc + (k>>5))*512 + (size_t)((((k&31)>>3)*16 + (n&15))*8 + (k&7));
}

// ---------------- element counts ----------------
constexpr size_t NXE   = 128ull*256*128;
constexpr size_t NPM   = 1024ull*4096;
constexpr size_t NWIH0 = 3072ull*384;
constexpr size_t NWIH12= 3072ull*256;
constexpr size_t NWIH3 = 3456ull*256;
constexpr size_t NWHH  = 3072ull*1024;
constexpr size_t NWHH3 = 3456ull*1152;
constexpr size_t NCTX  = 128ull*1024;
constexpr size_t NHMX  = 128ull*1152;

// ---------------- workspace offsets (bytes) ----------------
constexpr size_t OFF_XH    = 0;
constexpr size_t OFF_XL    = OFF_XH + NXE*2;
constexpr size_t OFF_PMH   = OFF_XL + NXE*2;
constexpr size_t OFF_PML   = OFF_PMH + NPM*2;
constexpr size_t OFF_WIHH0 = OFF_PML + NPM*2;
constexpr size_t OFF_WIHH1 = OFF_WIHH0 + NWIH0*2;
constexpr size_t OFF_WIHH2 = OFF_WIHH1 + NWIH12*2;
constexpr size_t OFF_WIHH3 = OFF_WIHH2 + NWIH12*2;
constexpr size_t OFF_WIHL0 = OFF_WIHH3 + NWIH3*2;
constexpr size_t OFF_WIHL1 = OFF_WIHL0 + NWIH0*2;
constexpr size_t OFF_WIHL2 = OFF_WIHL1 + NWIH12*2;
constexpr size_t OFF_WIHL3 = OFF_WIHL2 + NWIH12*2;
constexpr size_t OFF_WHHH0 = OFF_WIHL3 + NWIH3*2;
constexpr size_t OFF_WHHH1 = OFF_WHHH0 + NWHH*2;
constexpr size_t OFF_WHHH2 = OFF_WHHH1 + NWHH*2;
constexpr size_t OFF_WHHH3 = OFF_WHHH2 + NWHH*2;
constexpr size_t OFF_WHHL0 = OFF_WHHH3 + NWHH3*2;
constexpr size_t OFF_WHHL1 = OFF_WHHL0 + NWHH*2;
constexpr size_t OFF_WHHL2 = OFF_WHHL1 + NWHH*2;
constexpr size_t OFF_WHHL3 = OFF_WHHL2 + NWHH*2;
constexpr size_t OFF_C0H   = OFF_WHHL3 + NWHH3*2;   // center_init, h-layout, 4 modules
constexpr size_t OFF_C0L   = OFF_C0H + 4*NHMX*2;
constexpr size_t OFF_CTXH  = OFF_C0L + 4*NHMX*2;
constexpr size_t OFF_CTXL  = OFF_CTXH + NCTX*2;
constexpr size_t OFF_HH    = OFF_CTXL + NCTX*2;     // [(p*4+i)]
constexpr size_t OFF_HL    = OFF_HH + 8*NHMX*2;
constexpr size_t WS_NEED   = OFF_HL + 8*NHMX*2;     // ~109 MB

__device__ __forceinline__ f16* hh_ptr(char* ws,int p,int i){ return (f16*)(ws+OFF_HH+((size_t)(p*4+i))*NHMX*2); }
__device__ __forceinline__ f16* hl_ptr(char* ws,int p,int i){ return (f16*)(ws+OFF_HL+((size_t)(p*4+i))*NHMX*2); }

// ---------------- prep: repack to fragment-major ----------------
__global__ void k_repack_w(const float* __restrict__ src, f16* __restrict__ hi,
                           f16* __restrict__ lo, int K){
    int n = blockIdx.x;
    const float* row = src + (size_t)n*K;
    int Kc = K >> 5;
    for (int k8 = threadIdx.x*8; k8 < K; k8 += 2048) {
        f16x8 hv, lv;
        #pragma unroll
        for (int e = 0; e < 8; ++e) { f16 a,b; fsplit(row[k8+e], &a, &b); hv[e]=a; lv[e]=b; }
        size_t d = fragoff(n, k8, Kc);
        *reinterpret_cast<f16x8*>(hi + d) = hv;
        *reinterpret_cast<f16x8*>(lo + d) = lv;
    }
}

__global__ void k_repack_pm(const float* __restrict__ p0, const float* __restrict__ p1,
                            const float* __restrict__ p2, const float* __restrict__ p3,
                            f16* __restrict__ hi, f16* __restrict__ lo){
    int k0 = blockIdx.x * 8;
    for (int c = threadIdx.x; c < 1024; c += 256) {
        int i = c >> 8, nl = c & 255;
        const float* p = (i==0?p0 : i==1?p1 : i==2?p2 : p3);
        #pragma unroll
        for (int e = 0; e < 8; ++e) {
            f16 a,b; fsplit(p[(size_t)(k0+e)*256 + nl], &a, &b);
            size_t d = fragoff(c, k0+e, 128); hi[d]=a; lo[d]=b;
        }
    }
}

__global__ void k_repack_x(const float* __restrict__ src, f16* __restrict__ hi, f16* __restrict__ lo){
    size_t g = ((size_t)blockIdx.x*256 + threadIdx.x) * 8;
    if (g >= NXE) return;
    int m = (int)(g >> 15), t = (int)((g >> 7) & 255), d0 = (int)(g & 127);
    f16x8 hv, lv;
    #pragma unroll
    for (int e = 0; e < 8; ++e) { f16 a,b; fsplit(src[g+e], &a, &b); hv[e]=a; lv[e]=b; }
    size_t d = (size_t)t*16384 + fragoff(m, d0, 4);
    *reinterpret_cast<f16x8*>(hi + d) = hv;
    *reinterpret_cast<f16x8*>(lo + d) = lv;
}

__global__ void k_init_cen(const float* __restrict__ ci, char* ws){
    size_t g = ((size_t)blockIdx.x*256 + threadIdx.x) * 8;
    if (g >= 4ull*128*1024) return;
    int i = (int)(g >> 17), b = (int)((g >> 10) & 127), c = (int)(g & 1023);
    f16* hi = (f16*)(ws + OFF_C0H) + (size_t)i*NHMX;
    f16* lo = (f16*)(ws + OFF_C0L) + (size_t)i*NHMX;
    f16x8 hv, lv;
    #pragma unroll
    for (int e = 0; e < 8; ++e) { f16 a,bb; fsplit(ci[g+e], &a, &bb); hv[e]=a; lv[e]=bb; }
    size_t d = (i < 3) ? fragoff(b, c, 32) : fragoff(b, 128 + c, 36);
    *reinterpret_cast<f16x8*>(hi + d) = hv;
    *reinterpret_cast<f16x8*>(lo + d) = lv;
}

__global__ void k_init_mod(const float* __restrict__ mi, char* ws){
    size_t g = ((size_t)blockIdx.x*256 + threadIdx.x) * 8;
    if (g >= 3ull*128*1024) return;
    int i = (int)(g >> 17), b = (int)((g >> 10) & 127), j = (int)(g & 1023);
    f16 *hh = hh_ptr(ws, 0, i), *hl = hl_ptr(ws, 0, i);
    f16x8 hv, lv;
    #pragma unroll
    for (int e = 0; e < 8; ++e) { f16 a,bb; fsplit(mi[g+e], &a, &bb); hv[e]=a; lv[e]=bb; }
    size_t d = fragoff(b, j, 32);
    *reinterpret_cast<f16x8*>(hh + d) = hv;
    *reinterpret_cast<f16x8*>(hl + d) = lv;
}

__global__ void k_init_last(const float* __restrict__ ml, char* ws){
    int b = blockIdx.x;
    f16 *hh = hh_ptr(ws, 0, 3), *hl = hl_ptr(ws, 0, 3);
    for (int j = threadIdx.x*8; j < 1152; j += 2048) {
        f16x8 hv, lv;
        #pragma unroll
        for (int e = 0; e < 8; ++e) { f16 a,bb; fsplit(ml[(size_t)b*1152 + j + e], &a, &bb); hv[e]=a; lv[e]=bb; }
        size_t d = fragoff(b, j, 36);
        *reinterpret_cast<f16x8*>(hh + d) = hv;
        *reinterpret_cast<f16x8*>(hl + d) = lv;
    }
}

// ---------------- step kernel 1: ctx = center @ pm ----------------
// pm-sharing blocks (same bn, bm 0..3) differ by 64 in bid -> same XCD already.
__global__ __launch_bounds__(512) void k_ctx(char* ws, int par, int t){
    __shared__ float red[8][32][17];
    const f16* pmh  = (const f16*)(ws + OFF_PMH);
    const f16* pml  = (const f16*)(ws + OFF_PML);
    int tid = threadIdx.x, lane = tid & 63, wv = tid >> 6;
    int bm = blockIdx.x >> 6, bn = blockIdx.x & 63;
    int mod = wv >> 1, half = wv & 1;
    const int Kc_m = (mod == 3) ? 36 : 32;
    const int koff = ((mod == 3) ? 4 : 0) + half*16;
    const f16 *Ah, *Al;
    if (t == 0) {
        Ah = (const f16*)(ws + OFF_C0H) + (size_t)mod*NHMX;
        Al = (const f16*)(ws + OFF_C0L) + (size_t)mod*NHMX;
    } else {
        Ah = hh_ptr(ws, par, mod);
        Al = hl_ptr(ws, par, mod);
    }
    size_t lb = (size_t)lane*8;
    size_t a0 = ((size_t)(bm*2)*Kc_m + koff)*512 + lb;
    size_t a1 = a0 + (size_t)Kc_m*512;
    size_t bb = ((size_t)bn*128 + wv*16)*512 + lb;
    f32x4 h0={},h1={},c0={},c1={};
    #pragma unroll 4
    for (int kc = 0; kc < 16; ++kc) {
        f16x8 bh = ld8h(pmh + bb + kc*512), bl = ld8h(pml + bb + kc*512);
        f16x8 ah0 = ld8h(Ah + a0 + kc*512), al0 = ld8h(Al + a0 + kc*512);
        f16x8 ah1 = ld8h(Ah + a1 + kc*512), al1 = ld8h(Al + a1 + kc*512);
        h0 = MFMA16(ah0,bh,h0); c0 = MFMA16(al0,bh,c0); c0 = MFMA16(ah0,bl,c0);
        h1 = MFMA16(ah1,bh,h1); c1 = MFMA16(al1,bh,c1); c1 = MFMA16(ah1,bl,c1);
    }
    int rg = lane >> 4, fr = lane & 15;
    const float inv = 1.0f/4096.0f;
    #pragma unroll
    for (int rr = 0; rr < 4; ++rr) {
        red[wv][rg*4+rr][fr]      = h0[rr] + c0[rr]*inv;
        red[wv][16+rg*4+rr][fr]   = h1[rr] + c1[rr]*inv;
    }
    __syncthreads();
    int r = tid >> 4, c = tid & 15;
    float s = red[0][r][c]+red[1][r][c]+red[2][r][c]+red[3][r][c]
            + red[4][r][c]+red[5][r][c]+red[6][r][c]+red[7][r][c];
    int m = bm*32 + r, n = bn*16 + c;
    size_t d = fragoff(m, n, 32);
    f16* ctxh = (f16*)(ws + OFF_CTXH);
    f16* ctxl = (f16*)(ws + OFF_CTXL);
    fsplit(s, &ctxh[d], &ctxl[d]);
}

// ---------------- step kernel 2: fused gates+GRU, K-quarter, one barrier ----------------
// + XCD-pairing swizzle: lid=(bid&7)*66+(bid>>3) maps each tile's rh=0/1 pair
// to bids differing by 8 -> same XCD L2 -> B-slab fetched once per XCD instead of twice.
__global__ __launch_bounds__(512, 2) void k_fused(char* ws,
    const float* __restrict__ bih0, const float* __restrict__ bih1,
    const float* __restrict__ bih2, const float* __restrict__ bih3,
    const float* __restrict__ bhh0, const float* __restrict__ bhh1,
    const float* __restrict__ bhh2, const float* __restrict__ bhh3,
    float* __restrict__ out, int t, int par)
{
    __shared__ float red[3][4][64][17];   // [kq-1][slot R,Z,I,N][local row][col] = 52.2 KB
    const int tid = threadIdx.x, lane = tid & 63, wv = tid >> 6;
    const int kq = wv & 3, mp = wv >> 2;
    const int fr = lane & 15, rg = lane >> 4;
    const int lid = (blockIdx.x & 7)*66 + (blockIdx.x >> 3);   // XCD-pairing swizzle
    const int tile = lid >> 1, rh = lid & 1;
    int i, jt;
    if (tile < 64)       { i = 0; jt = tile; }
    else if (tile < 128) { i = 1; jt = tile - 64; }
    else if (tile < 192) { i = 2; jt = tile - 128; }
    else                 { i = 3; jt = tile - 192; }
    const int H  = (i == 3) ? 1152 : 1024;
    const int K1 = (i == 0) ? 384 : 256;
    const int Kc1 = K1 >> 5, KcH = H >> 5, Ht = H >> 4;
    const int P1q = Kc1 >> 2, PHq = KcH >> 2;    // 3|2 and 8|9 — exact

    const f16* WihH = (const f16*)(ws + (i==0?OFF_WIHH0 : i==1?OFF_WIHH1 : i==2?OFF_WIHH2 : OFF_WIHH3));
    const f16* WihL = (const f16*)(ws + (i==0?OFF_WIHL0 : i==1?OFF_WIHL1 : i==2?OFF_WIHL2 : OFF_WIHL3));
    const f16* WhhH = (const f16*)(ws + (i==0?OFF_WHHH0 : i==1?OFF_WHHH1 : i==2?OFF_WHHH2 : OFF_WHHH3));
    const f16* WhhL = (const f16*)(ws + (i==0?OFF_WHHL0 : i==1?OFF_WHHL1 : i==2?OFF_WHHL2 : OFF_WHHL3));

    const size_t lb = (size_t)lane*8;
    size_t b1[3], b2[3];
    #pragma unroll
    for (int s = 0; s < 3; ++s) {
        b1[s] = ((size_t)(s*Ht + jt)*Kc1)*512 + lb;
        b2[s] = ((size_t)(s*Ht + jt)*KcH)*512 + lb;
    }
    const int mt0 = rh*4 + mp*2;   // global m-frag base (2 frags = 32 rows)

    f32x4 aRh[2]={{},{}}, aRc[2]={{},{}}, aZh[2]={{},{}}, aZc[2]={{},{}};
    f32x4 aIh[2]={{},{}}, aIc[2]={{},{}}, aNh[2]={{},{}}, aNc[2]={{},{}};

    // ---- ih GEMM (K-quarter): A = (i==0 ? [x_t | ctx0] : ctx_i) ----
    {
        const f16* XH_ = (const f16*)(ws + OFF_XH);
        const f16* XL_ = (const f16*)(ws + OFF_XL);
        const f16* CH_ = (const f16*)(ws + OFF_CTXH);
        const f16* CL_ = (const f16*)(ws + OFF_CTXL);
        size_t xb0 = ((size_t)(t*8 + mt0)*4)*512 + lb, xb1 = xb0 + 2048;
        size_t cb0 = ((size_t)mt0*32)*512 + lb,        cb1 = cb0 + 16384;
        const int kc0 = kq*P1q, kc1e = kc0 + P1q;
        #pragma unroll 2
        for (int kc = kc0; kc < kc1e; ++kc) {
            f16x8 ah0, al0, ah1, al1;
            if (i == 0 && kc < 4) {
                ah0 = ld8h(XH_ + xb0 + kc*512); al0 = ld8h(XL_ + xb0 + kc*512);
                ah1 = ld8h(XH_ + xb1 + kc*512); al1 = ld8h(XL_ + xb1 + kc*512);
            } else {
                const int ck = (i == 0) ? kc - 4 : i*8 + kc;
                ah0 = ld8h(CH_ + cb0 + ck*512); al0 = ld8h(CL_ + cb0 + ck*512);
                ah1 = ld8h(CH_ + cb1 + ck*512); al1 = ld8h(CL_ + cb1 + ck*512);
            }
            f16x8 bh, bl;
            bh = ld8h(WihH + b1[0] + kc*512); bl = ld8h(WihL + b1[0] + kc*512);
            aRh[0]=MFMA16(ah0,bh,aRh[0]); aRc[0]=MFMA16(al0,bh,aRc[0]); aRc[0]=MFMA16(ah0,bl,aRc[0]);
            aRh[1]=MFMA16(ah1,bh,aRh[1]); aRc[1]=MFMA16(al1,bh,aRc[1]); aRc[1]=MFMA16(ah1,bl,aRc[1]);
            bh = ld8h(WihH + b1[1] + kc*512); bl = ld8h(WihL + b1[1] + kc*512);
            aZh[0]=MFMA16(ah0,bh,aZh[0]); aZc[0]=MFMA16(al0,bh,aZc[0]); aZc[0]=MFMA16(ah0,bl,aZc[0]);
            aZh[1]=MFMA16(ah1,bh,aZh[1]); aZc[1]=MFMA16(al1,bh,aZc[1]); aZc[1]=MFMA16(ah1,bl,aZc[1]);
            bh = ld8h(WihH + b1[2] + kc*512); bl = ld8h(WihL + b1[2] + kc*512);
            aIh[0]=MFMA16(ah0,bh,aIh[0]); aIc[0]=MFMA16(al0,bh,aIc[0]); aIc[0]=MFMA16(ah0,bl,aIc[0]);
            aIh[1]=MFMA16(ah1,bh,aIh[1]); aIc[1]=MFMA16(al1,bh,aIc[1]); aIc[1]=MFMA16(ah1,bl,aIc[1]);
        }
    }
    // ---- hh GEMM (K-quarter): A = h_prev (parity par) ----
    {
        const f16* HHp = hh_ptr(ws, par, i);
        const f16* HLp = hl_ptr(ws, par, i);
        size_t hb0 = ((size_t)mt0*KcH)*512 + lb, hb1 = hb0 + (size_t)KcH*512;
        const int kc0 = kq*PHq, kc1e = kc0 + PHq;
        #pragma unroll 2
        for (int kc = kc0; kc < kc1e; ++kc) {
            f16x8 ah0 = ld8h(HHp + hb0 + kc*512), al0 = ld8h(HLp + hb0 + kc*512);
            f16x8 ah1 = ld8h(HHp + hb1 + kc*512), al1 = ld8h(HLp + hb1 + kc*512);
            f16x8 bh, bl;
            bh = ld8h(WhhH + b2[0] + kc*512); bl = ld8h(WhhL + b2[0] + kc*512);
            aRh[0]=MFMA16(ah0,bh,aRh[0]); aRc[0]=MFMA16(al0,bh,aRc[0]); aRc[0]=MFMA16(ah0,bl,aRc[0]);
            aRh[1]=MFMA16(ah1,bh,aRh[1]); aRc[1]=MFMA16(al1,bh,aRc[1]); aRc[1]=MFMA16(ah1,bl,aRc[1]);
            bh = ld8h(WhhH + b2[1] + kc*512); bl = ld8h(WhhL + b2[1] + kc*512);
            aZh[0]=MFMA16(ah0,bh,aZh[0]); aZc[0]=MFMA16(al0,bh,aZc[0]); aZc[0]=MFMA16(ah0,bl,aZc[0]);
            aZh[1]=MFMA16(ah1,bh,aZh[1]); aZc[1]=MFMA16(al1,bh,aZc[1]); aZc[1]=MFMA16(ah1,bl,aZc[1]);
            bh = ld8h(WhhH + b2[2] + kc*512); bl = ld8h(WhhL + b2[2] + kc*512);
            aNh[0]=MFMA16(ah0,bh,aNh[0]); aNc[0]=MFMA16(al0,bh,aNc[0]); aNc[0]=MFMA16(ah0,bl,aNc[0]);
            aNh[1]=MFMA16(ah1,bh,aNh[1]); aNc[1]=MFMA16(al1,bh,aNc[1]); aNc[1]=MFMA16(ah1,bl,aNc[1]);
        }
    }

    const float inv = 1.0f/4096.0f;
    const int r16 = rg*4;
    // ---- kq 1..3 deposit partials into independent buffers ----
    if (kq != 0) {
        #pragma unroll
        for (int mi = 0; mi < 2; ++mi) {
            #pragma unroll
            for (int rr = 0; rr < 4; ++rr) {
                const int row = mp*32 + mi*16 + r16 + rr;
                red[kq-1][0][row][fr] = aRh[mi][rr] + aRc[mi][rr]*inv;
                red[kq-1][1][row][fr] = aZh[mi][rr] + aZc[mi][rr]*inv;
                red[kq-1][2][row][fr] = aIh[mi][rr] + aIc[mi][rr]*inv;
                red[kq-1][3][row][fr] = aNh[mi][rr] + aNc[mi][rr]*inv;
            }
        }
    }
    __syncthreads();
    if (kq != 0) return;

    // ---- kq=0 waves (mp 0,1): combine + GRU epilogue, 32 rows each ----
    const float* bihp = (i==0?bih0 : i==1?bih1 : i==2?bih2 : bih3);
    const float* bhhp = (i==0?bhh0 : i==1?bhh1 : i==2?bhh2 : bhh3);
    const int j = jt*16 + fr;
    const float bir = bihp[j], biz = bihp[H+j], bin = bihp[2*H+j];
    const float bhr = bhhp[j], bhz = bhhp[H+j], bhn = bhhp[2*H+j];
    const f16* hhP = hh_ptr(ws, par, i);
    const f16* hlP = hl_ptr(ws, par, i);
    f16 *hhN = hh_ptr(ws, par^1, i), *hlN = hl_ptr(ws, par^1, i);
    #pragma unroll
    for (int mi = 0; mi < 2; ++mi) {
        #pragma unroll
        for (int rr = 0; rr < 4; ++rr) {
            const int row = mp*32 + mi*16 + r16 + rr;
            float r_  = aRh[mi][rr] + aRc[mi][rr]*inv
                      + red[0][0][row][fr] + red[1][0][row][fr] + red[2][0][row][fr] + bir + bhr;
            float z_  = aZh[mi][rr] + aZc[mi][rr]*inv
                      + red[0][1][row][fr] + red[1][1][row][fr] + red[2][1][row][fr] + biz + bhz;
            float in_ = aIh[mi][rr] + aIc[mi][rr]*inv
                      + red[0][2][row][fr] + red[1][2][row][fr] + red[2][2][row][fr] + bin;
            float hn_ = aNh[mi][rr] + aNc[mi][rr]*inv
                      + red[0][3][row][fr] + red[1][3][row][fr] + red[2][3][row][fr] + bhn;
            float rgt = 1.f/(1.f + expf(-r_));
            float zgt = 1.f/(1.f + expf(-z_));
            float ngt = tanhf(in_ + rgt*hn_);
            const int m = rh*64 + row;
            size_t hd = fragoff(m, j, KcH);
            float hp = (float)hhP[hd] + (float)hlP[hd]*inv;
            float hnew = (1.f - zgt)*ngt + zgt*hp;
            fsplit(hnew, &hhN[hd], &hlN[hd]);
            if (i == 3 && j < 128)
                out[((size_t)m*256 + t)*128 + j] = hnew;
        }
    }
}

// ---------------- host ----------------
extern "C" void kernel_launch(void* const* d_in, const int* in_sizes, int n_in,
                              void* d_out, int out_size, void* d_ws, size_t ws_size,
                              hipStream_t stream)
{
    char* ws = (char*)d_ws;
    const float* inp   = (const float*)d_in[0];
    const float* cini  = (const float*)d_in[1];
    const float* mini  = (const float*)d_in[2];
    const float* mlast = (const float*)d_in[3];
    const float *pm[4], *wih[4], *whh[4], *bih[4], *bhh[4];
    for (int i = 0; i < 4; ++i) {
        pm[i]  = (const float*)d_in[4 + 5*i];
        wih[i] = (const float*)d_in[5 + 5*i];
        whh[i] = (const float*)d_in[6 + 5*i];
        bih[i] = (const float*)d_in[7 + 5*i];
        bhh[i] = (const float*)d_in[8 + 5*i];
    }
    float* out = (float*)d_out;

    k_repack_x<<<2048, 256, 0, stream>>>(inp, (f16*)(ws+OFF_XH), (f16*)(ws+OFF_XL));
    k_repack_pm<<<512, 256, 0, stream>>>(pm[0], pm[1], pm[2], pm[3],
                                         (f16*)(ws+OFF_PMH), (f16*)(ws+OFF_PML));
    k_repack_w<<<3072, 256, 0, stream>>>(wih[0], (f16*)(ws+OFF_WIHH0), (f16*)(ws+OFF_WIHL0), 384);
    k_repack_w<<<3072, 256, 0, stream>>>(wih[1], (f16*)(ws+OFF_WIHH1), (f16*)(ws+OFF_WIHL1), 256);
    k_repack_w<<<3072, 256, 0, stream>>>(wih[2], (f16*)(ws+OFF_WIHH2), (f16*)(ws+OFF_WIHL2), 256);
    k_repack_w<<<3456, 256, 0, stream>>>(wih[3], (f16*)(ws+OFF_WIHH3), (f16*)(ws+OFF_WIHL3), 256);
    k_repack_w<<<3072, 256, 0, stream>>>(whh[0], (f16*)(ws+OFF_WHHH0), (f16*)(ws+OFF_WHHL0), 1024);
    k_repack_w<<<3072, 256, 0, stream>>>(whh[1], (f16*)(ws+OFF_WHHH1), (f16*)(ws+OFF_WHHL1), 1024);
    k_repack_w<<<3072, 256, 0, stream>>>(whh[2], (f16*)(ws+OFF_WHHH2), (f16*)(ws+OFF_WHHL2), 1024);
    k_repack_w<<<3456, 256, 0, stream>>>(whh[3], (f16*)(ws+OFF_WHHH3), (f16*)(ws+OFF_WHHL3), 1152);
    k_init_cen<<<256, 256, 0, stream>>>(cini, ws);
    k_init_mod<<<192, 256, 0, stream>>>(mini, ws);
    k_init_last<<<128, 256, 0, stream>>>(mlast, ws);

    for (int t = 0; t < 256; ++t) {
        int par = t & 1;
        k_ctx<<<256, 512, 0, stream>>>(ws, par, t);
        k_fused<<<528, 512, 0, stream>>>(ws,
            bih[0], bih[1], bih[2], bih[3],
            bhh[0], bhh[1], bhh[2], bhh[3],
            out, t, par);
    }
    (void)in_sizes; (void)n_in; (void)out_size; (void)ws_size; (void)WS_NEED;
}